// Round 3
// baseline (579.984 us; speedup 1.0000x reference)
//
#include <hip/hip_runtime.h>
#include <hip/hip_bf16.h>

#define B_ 4
#define S_ 4096
#define E_ 1024
#define H_ 16
#define D_ 64
#define NS_ 1024
#define M_ (B_*S_)
#define K_ E_
#define DELTA 0.12f
#define BANDCAP 96

typedef __attribute__((ext_vector_type(8))) short bf16x8;
typedef __attribute__((ext_vector_type(4))) float floatx4;
typedef __attribute__((ext_vector_type(2))) float f32x2;

#define THSTEP 0.00038349519697141023f  /* (pi/2)/4096 */

__device__ inline float bf16_to_f(unsigned short u) {
    return __uint_as_float(((unsigned)u) << 16);
}
__device__ inline unsigned short f_to_bf16(float f) {
    unsigned u = __float_as_uint(f);
    unsigned r = (u + 0x7FFFu + ((u >> 16) & 1u)) >> 16;  // RNE
    return (unsigned short)r;
}

// async global->LDS DMA, 16B per lane, wave-uniform LDS base + lane*16 dest.
__device__ inline void gl_lds16(const void* g, void* l) {
    __builtin_amdgcn_global_load_lds(
        (const __attribute__((address_space(1))) void*)g,
        (__attribute__((address_space(3))) void*)l, 16, 0, 0);
}

// ---------------------------------------------------------------------------
// Prep kernel: fuses {zero(out), x->xh bf16, W splits}.  4096 blocks x 256.
// t in [0, 1M): 4 uint4 zeros + 4 float4 x-splits each; t<256K does W split.
// ---------------------------------------------------------------------------
__global__ __launch_bounds__(256) void prep_kernel(
    const float* __restrict__ x,
    const float* __restrict__ Wq, const float* __restrict__ Wk,
    const float* __restrict__ Wv,
    ushort* __restrict__ xh,
    ushort* __restrict__ Wqh, ushort* __restrict__ Wql,
    ushort* __restrict__ Wkh, ushort* __restrict__ Wkl,
    ushort* __restrict__ Wvh,
    uint4* __restrict__ outz)
{
    int t = blockIdx.x * 256 + threadIdx.x;     // 0 .. 1,048,575
    uint4 z = make_uint4(0u, 0u, 0u, 0u);
#pragma unroll
    for (int c = 0; c < 4; ++c)
        outz[c * 1048576 + t] = z;               // 4M uint4 = 64MB out
#pragma unroll
    for (int c = 0; c < 4; ++c) {
        int i = c * 1048576 + t;                 // 4M float4 of x
        float4 v = ((const float4*)x)[i];
        ushort4 hh;
        hh.x = f_to_bf16(v.x); hh.y = f_to_bf16(v.y);
        hh.z = f_to_bf16(v.z); hh.w = f_to_bf16(v.w);
        ((ushort4*)xh)[i] = hh;
    }
    if (t < 262144) {                            // 256K float4 per W matrix
        int i = t;
        float4 q = ((const float4*)Wq)[i];
        float4 k = ((const float4*)Wk)[i];
        float4 v = ((const float4*)Wv)[i];
        ushort4 h, l;
        h.x=f_to_bf16(q.x); l.x=f_to_bf16(q.x-bf16_to_f(h.x));
        h.y=f_to_bf16(q.y); l.y=f_to_bf16(q.y-bf16_to_f(h.y));
        h.z=f_to_bf16(q.z); l.z=f_to_bf16(q.z-bf16_to_f(h.z));
        h.w=f_to_bf16(q.w); l.w=f_to_bf16(q.w-bf16_to_f(h.w));
        ((ushort4*)Wqh)[i]=h; ((ushort4*)Wql)[i]=l;
        h.x=f_to_bf16(k.x); l.x=f_to_bf16(k.x-bf16_to_f(h.x));
        h.y=f_to_bf16(k.y); l.y=f_to_bf16(k.y-bf16_to_f(h.y));
        h.z=f_to_bf16(k.z); l.z=f_to_bf16(k.z-bf16_to_f(h.z));
        h.w=f_to_bf16(k.w); l.w=f_to_bf16(k.w-bf16_to_f(h.w));
        ((ushort4*)Wkh)[i]=h; ((ushort4*)Wkl)[i]=l;
        h.x=f_to_bf16(v.x); h.y=f_to_bf16(v.y);
        h.z=f_to_bf16(v.z); h.w=f_to_bf16(v.w);
        ((ushort4*)Wvh)[i]=h;
    }
}

// ---------------------------------------------------------------------------
// Kernel 1: QKV GEMM, split into 3 launches (q, k, v) for profiling
// visibility + per-pass LDS sizing.  LO=1: hi+lo B (fp32 out); LO=0: hi only
// (bf16 out, 32KB LDS -> higher occupancy).
// global_load_lds staging, XCD-grouped grid dim3(128, 8).
// ---------------------------------------------------------------------------
template<int LO>
__global__ __launch_bounds__(256) void qkv_gemm_t(
    const ushort* __restrict__ xh,
    const ushort* __restrict__ Bhp, const ushort* __restrict__ Blp,
    const float* __restrict__ bias,
    float* __restrict__ o32, ushort* __restrict__ o16)
{
    __shared__ __align__(16) ushort As[128 * 64];
    __shared__ __align__(16) ushort Bsh[128 * 64];
    __shared__ __align__(16) ushort Bsl[LO ? 128 * 64 : 8];

    const int m0 = blockIdx.x * 128;
    const int n0 = blockIdx.y * 128;
    const int t = threadIdx.x;
    const int wave = t >> 6, lane = t & 63;
    const int wm = (wave >> 1) * 64, wn = (wave & 1) * 64;
    const int m16 = lane & 15, quad = lane >> 4;

    floatx4 acc[4][4];
#pragma unroll
    for (int i = 0; i < 4; i++)
#pragma unroll
        for (int j = 0; j < 4; j++) acc[i][j] = (floatx4){0.f, 0.f, 0.f, 0.f};

    int aoff[4], boff[4], lbase[4];
#pragma unroll
    for (int i = 0; i < 4; i++) {
        int slot = i * 256 + t;
        int r = slot >> 3, c = slot & 7, g = c ^ (r & 7);
        aoff[i] = (m0 + r) * K_ + g * 8;
        boff[i] = (n0 + r) * K_ + g * 8;
        lbase[i] = (i * 256 + wave * 64) * 8;   // wave-uniform LDS element base
    }

    for (int ks = 0; ks < 16; ++ks) {
        const int kcol = ks * 64;
#pragma unroll
        for (int i = 0; i < 4; i++) {
            gl_lds16(xh + aoff[i] + kcol, &As[lbase[i]]);
            gl_lds16(Bhp + boff[i] + kcol, &Bsh[lbase[i]]);
        }
        if constexpr (LO) {
#pragma unroll
            for (int i = 0; i < 4; i++)
                gl_lds16(Blp + boff[i] + kcol, &Bsl[lbase[i]]);
        }
        __syncthreads();

#pragma unroll
        for (int kk = 0; kk < 2; ++kk) {
            bf16x8 af[4], bfr[4];
            const int g = kk * 4 + quad;
#pragma unroll
            for (int mt = 0; mt < 4; ++mt) {
                int r = wm + mt * 16 + m16;
                af[mt] = *(const bf16x8*)&As[(r * 8 + (g ^ (r & 7))) * 8];
            }
#pragma unroll
            for (int nt = 0; nt < 4; ++nt) {
                int r2 = wn + nt * 16 + m16;
                bfr[nt] = *(const bf16x8*)&Bsh[(r2 * 8 + (g ^ (r2 & 7))) * 8];
            }
#pragma unroll
            for (int mt = 0; mt < 4; ++mt)
#pragma unroll
                for (int nt = 0; nt < 4; ++nt)
                    acc[mt][nt] = __builtin_amdgcn_mfma_f32_16x16x32_bf16(
                        af[mt], bfr[nt], acc[mt][nt], 0, 0, 0);
            if constexpr (LO) {
#pragma unroll
                for (int nt = 0; nt < 4; ++nt) {
                    int r2 = wn + nt * 16 + m16;
                    bfr[nt] = *(const bf16x8*)&Bsl[(r2 * 8 + (g ^ (r2 & 7))) * 8];
                }
#pragma unroll
                for (int mt = 0; mt < 4; ++mt)
#pragma unroll
                    for (int nt = 0; nt < 4; ++nt)
                        acc[mt][nt] = __builtin_amdgcn_mfma_f32_16x16x32_bf16(
                            af[mt], bfr[nt], acc[mt][nt], 0, 0, 0);
            }
        }
        __syncthreads();
    }

    float biasv[4];
#pragma unroll
    for (int nt = 0; nt < 4; nt++)
        biasv[nt] = bias[n0 + wn + nt * 16 + m16];

    if constexpr (LO) {
#pragma unroll
        for (int mt = 0; mt < 4; ++mt)
#pragma unroll
            for (int nt = 0; nt < 4; ++nt) {
                int colg = n0 + wn + nt * 16 + m16;
#pragma unroll
                for (int reg = 0; reg < 4; ++reg) {
                    int rowg = m0 + wm + mt * 16 + quad * 4 + reg;
                    o32[(size_t)rowg * E_ + colg] = acc[mt][nt][reg] + biasv[nt];
                }
            }
    } else {
#pragma unroll
        for (int mt = 0; mt < 4; ++mt)
#pragma unroll
            for (int nt = 0; nt < 4; ++nt) {
                int colg = n0 + wn + nt * 16 + m16;
#pragma unroll
                for (int reg = 0; reg < 4; ++reg) {
                    int rowg = m0 + wm + mt * 16 + quad * 4 + reg;
                    o16[(size_t)rowg * E_ + colg] = f_to_bf16(acc[mt][nt][reg] + biasv[nt]);
                }
            }
    }
}

// ---------------------------------------------------------------------------
// Kernel 2: scores[b,h,s] = sum_d q*k.  float4/lane, one token per 16-lane
// group (4 tokens/wave).
// ---------------------------------------------------------------------------
__global__ __launch_bounds__(256) void scores_kernel(
    const float* __restrict__ q32, const float* __restrict__ k32,
    float* __restrict__ scores)
{
    int g = blockIdx.x * 16 + (threadIdx.x >> 4);    // token slot == (bh<<12)|s
    int sub = threadIdx.x & 15;
    int s = g & (S_ - 1);
    int bh = g >> 12;
    int b = bh >> 4, h = bh & 15;
    size_t addr = (size_t)(b * S_ + s) * E_ + h * 64 + sub * 4;
    float4 qv = *(const float4*)(q32 + addr);
    float4 kv = *(const float4*)(k32 + addr);
    float p = qv.x * kv.x + qv.y * kv.y + qv.z * kv.z + qv.w * kv.w;
#pragma unroll
    for (int m = 8; m; m >>= 1) p += __shfl_xor(p, m, 64);  // within 16-lane group
    if (sub == 0) scores[g] = p;
}

// ---------------------------------------------------------------------------
// Kernel 3: radix-select 1024th approx score T_a; classify into definite-in
// (> T_a+DELTA) and band (|score-T_a| <= DELTA).
// ---------------------------------------------------------------------------
__global__ __launch_bounds__(256) void band_select_kernel(
    const float* __restrict__ scores, int* __restrict__ selidx,
    int* __restrict__ band, int* __restrict__ meta)
{
    __shared__ unsigned keys[4096];
    __shared__ unsigned hist[256];
    __shared__ unsigned suf[256];
    __shared__ unsigned bcast[2];
    __shared__ int cnt_in, cnt_band;

    int bh = blockIdx.x;
    int t = threadIdx.x;
    const float* sc = scores + (size_t)bh * S_;

    for (int i = t; i < 4096; i += 256) {
        unsigned u = __float_as_uint(sc[i]);
        u = (u & 0x80000000u) ? ~u : (u | 0x80000000u);
        keys[i] = u;
    }
    if (t == 0) { cnt_in = 0; cnt_band = 0; }
    __syncthreads();

    unsigned prefix = 0, want = NS_;
    for (int shift = 24; shift >= 0; shift -= 8) {
        hist[t] = 0;
        __syncthreads();
        unsigned pmask = (shift == 24) ? 0u : (0xFFFFFFFFu << (shift + 8));
        for (int i = t; i < 4096; i += 256) {
            unsigned ky = keys[i];
            if ((ky & pmask) == prefix) atomicAdd(&hist[(ky >> shift) & 255u], 1u);
        }
        __syncthreads();
        suf[t] = hist[t];
        __syncthreads();
        for (int off = 1; off < 256; off <<= 1) {
            unsigned add = (t + off < 256) ? suf[t + off] : 0u;
            __syncthreads();
            suf[t] += add;
            __syncthreads();
        }
        unsigned Sb = suf[t];
        unsigned Snx = (t < 255) ? suf[t + 1] : 0u;
        if (Sb >= want && Snx < want) {
            bcast[0] = (unsigned)t;
            bcast[1] = want - Snx;
        }
        __syncthreads();
        prefix = prefix | (bcast[0] << shift);
        want = bcast[1];
        __syncthreads();
    }
    unsigned fb = (prefix & 0x80000000u) ? (prefix ^ 0x80000000u) : ~prefix;
    float Ta = __uint_as_float(fb);
    float Thi = Ta + DELTA, Tlo = Ta - DELTA;

    int* sel = selidx + (size_t)bh * NS_;
    int* bnd = band + (size_t)bh * BANDCAP;
    for (int i = t; i < 4096; i += 256) {
        float v = sc[i];
        if (v > Thi) {
            int p = atomicAdd(&cnt_in, 1);
            sel[p] = i;
        } else if (v >= Tlo) {
            int p = atomicAdd(&cnt_band, 1);
            if (p < BANDCAP) bnd[p] = i;
        }
    }
    __syncthreads();
    if (t == 0) {
        meta[bh * 2 + 0] = cnt_in;
        meta[bh * 2 + 1] = (cnt_band < BANDCAP) ? cnt_band : BANDCAP;
    }
}

// ---------------------------------------------------------------------------
// Kernel 4: exact fp64 band rescoring, 4 independent fp64 accumulators.
// ---------------------------------------------------------------------------
__global__ __launch_bounds__(512) void band_exact_kernel(
    const float* __restrict__ x,
    const float* __restrict__ Wq, const float* __restrict__ Wk,
    const int* __restrict__ band, const int* __restrict__ meta,
    double* __restrict__ bscore)
{
    int j = blockIdx.x, bh = blockIdx.y;
    int NB = meta[bh * 2 + 1];
    if (j >= NB) return;
    int b = bh >> 4, h = bh & 15;
    int s = band[(size_t)bh * BANDCAP + j];
    int t = threadIdx.x;
    int wave = t >> 6, lane = t & 63;

    __shared__ float xs[1024];
    __shared__ double qkd[128];     // [0:64)=q dots, [64:128)=k dots

    if (t < 256)
        *(float4*)&xs[t * 4] = *(const float4*)(x + (size_t)(b * S_ + s) * K_ + t * 4);
    __syncthreads();

    const float* Wbase = (wave < 4) ? Wq : Wk;
    int role = wave >> 2;
    int dbase = (wave & 3) * 16;
    const float4* xs4 = (const float4*)xs;

    for (int rr = 0; rr < 16; ++rr) {
        int d = dbase + rr;
        const float4* wrow4 = (const float4*)(Wbase + (size_t)(h * 64 + d) * K_);
        double a0 = 0.0, a1 = 0.0, a2 = 0.0, a3 = 0.0;
#pragma unroll
        for (int p = 0; p < 4; ++p) {
            float4 wv = wrow4[lane + 64 * p];
            float4 xv = xs4[lane + 64 * p];
            a0 += (double)xv.x * wv.x;
            a1 += (double)xv.y * wv.y;
            a2 += (double)xv.z * wv.z;
            a3 += (double)xv.w * wv.w;
        }
        double a = (a0 + a1) + (a2 + a3);
#pragma unroll
        for (int m = 32; m; m >>= 1) a += __shfl_xor(a, m, 64);
        if (lane == 0) qkd[role * 64 + d] = a;
    }
    __syncthreads();

    if (t < 64) {
        double p = qkd[t] * qkd[64 + t];
#pragma unroll
        for (int m = 32; m; m >>= 1) p += __shfl_xor(p, m, 64);
        if (t == 0) bscore[(size_t)bh * BANDCAP + j] = p;
    }
}

// Kernel 5: rank band tokens (ties -> lower index), fill selidx positions.
__global__ __launch_bounds__(128) void band_rank_kernel(
    const double* __restrict__ bscore, const int* __restrict__ band,
    const int* __restrict__ meta, int* __restrict__ selidx)
{
    __shared__ double sc[BANDCAP];
    __shared__ int bi[BANDCAP];
    int bh = blockIdx.x, t = threadIdx.x;
    int cnt_in = meta[bh * 2 + 0], NB = meta[bh * 2 + 1];
    int need = NS_ - cnt_in;
    if (t < NB) {
        sc[t] = bscore[(size_t)bh * BANDCAP + t];
        bi[t] = band[(size_t)bh * BANDCAP + t];
    }
    __syncthreads();
    if (t < NB) {
        double mine = sc[t]; int myi = bi[t]; int r = 0;
        for (int j2 = 0; j2 < NB; ++j2)
            r += (sc[j2] > mine) || (sc[j2] == mine && bi[j2] < myi);
        if (r < need) selidx[(size_t)bh * NS_ + cnt_in + r] = myi;
    }
}

// ---------------------------------------------------------------------------
// Kernel 6: partial KV reductions (R1 scalar-fmaf form, reverted from f32x2).
// ---------------------------------------------------------------------------
__global__ __launch_bounds__(256) void kv_partial_kernel(
    const float* __restrict__ k32, const ushort* __restrict__ v16,
    float* __restrict__ kvp)
{
    __shared__ float kls[16 * 64];
    __shared__ float vls[16 * 64];
    int ch = blockIdx.x;   // 0..15
    int bh = blockIdx.y;   // 0..63
    int b = bh >> 4, h = bh & 15;
    int t = threadIdx.x;
    int d0 = (t >> 4) * 4, e0 = (t & 15) * 4;
    int lr = t >> 4, lc = (t & 15) * 4;   // staging map: row, col4

    float accC[4][4] = {}, accS[4][4] = {};
    const float* kbase = k32 + (size_t)b * S_ * E_ + h * 64;
    const ushort* vbase = v16 + (size_t)b * S_ * E_ + h * 64;
    int s0 = ch * 256;

    for (int g = 0; g < 16; ++g) {
        int srow = s0 + g * 16 + lr;
        float4 kf = *(const float4*)(kbase + (size_t)srow * E_ + lc);
        ushort4 vu = *(const ushort4*)(vbase + (size_t)srow * E_ + lc);
        __syncthreads();
        *(float4*)&kls[lr * 64 + lc] = kf;
        float4 vf = { bf16_to_f(vu.x), bf16_to_f(vu.y),
                      bf16_to_f(vu.z), bf16_to_f(vu.w) };
        *(float4*)&vls[lr * 64 + lc] = vf;
        __syncthreads();
#pragma unroll 4
        for (int si = 0; si < 16; ++si) {
            int s = s0 + g * 16 + si;
            float th = (float)s * THSTEP;
            float cw = __cosf(th), sw = __sinf(th);
            float4 kf2 = *(const float4*)&kls[si * 64 + d0];
            float4 vf2 = *(const float4*)&vls[si * 64 + e0];
            float kr[4] = { fmaxf(kf2.x, 0.f), fmaxf(kf2.y, 0.f),
                            fmaxf(kf2.z, 0.f), fmaxf(kf2.w, 0.f) };
            float vv[4] = { vf2.x, vf2.y, vf2.z, vf2.w };
            float kc[4], ksn[4];
#pragma unroll
            for (int i = 0; i < 4; i++) { kc[i] = kr[i] * cw; ksn[i] = kr[i] * sw; }
#pragma unroll
            for (int i = 0; i < 4; i++)
#pragma unroll
                for (int jj = 0; jj < 4; jj++) {
                    accC[i][jj] += kc[i] * vv[jj];
                    accS[i][jj] += ksn[i] * vv[jj];
                }
        }
    }
    float* pc = kvp + ((size_t)(bh * 16 + ch) * 2) * 4096;
    float* ps = pc + 4096;
#pragma unroll
    for (int i = 0; i < 4; i++)
#pragma unroll
        for (int jj = 0; jj < 4; jj++) {
            pc[(d0 + i) * 64 + (e0 + jj)] = accC[i][jj];
            ps[(d0 + i) * 64 + (e0 + jj)] = accS[i][jj];
        }
}

// Kernel 7: reduce the 16 partials -> kv[bh][{cos,sin}][64][64]
__global__ __launch_bounds__(256) void kv_reduce_kernel(
    const float* __restrict__ kvp, float* __restrict__ kv)
{
    int i = blockIdx.x * 256 + threadIdx.x;   // 0 .. 64*2*4096-1
    if (i >= 64 * 2 * 4096) return;
    int bh = i >> 13;
    int rem = i & 8191;
    const float* p = kvp + (size_t)bh * 16 * 8192 + rem;
    float a = 0.f;
#pragma unroll
    for (int c = 0; c < 16; c++) a += p[c * 8192];
    kv[i] = a;
}

// ---------------------------------------------------------------------------
// Kernel 8: sampled = qs_cos @ kv_cos + qs_sin @ kv_sin, scattered to out.
// grid (16,64), 64 tokens/block, thread = (token, e-quarter).
// ---------------------------------------------------------------------------
__global__ __launch_bounds__(256) void sampled_kernel(
    const float* __restrict__ q32, const int* __restrict__ selidx,
    const float* __restrict__ kv, float* __restrict__ out)
{
    __shared__ __align__(16) float kvc[4096];
    __shared__ __align__(16) float kvs[4096];
    __shared__ __align__(16) float qs[64 * 68];   // stride 68: 16B-aligned rows
    __shared__ int sidx[64];
    int bh = blockIdx.y;
    int b = bh >> 4, h = bh & 15;
    int t = threadIdx.x;

    const float4* kvsrc4 = (const float4*)(kv + (size_t)bh * 8192);
    float4* kvc4 = (float4*)kvc;
    float4* kvs4 = (float4*)kvs;
#pragma unroll
    for (int i = 0; i < 4; ++i) {
        kvc4[i * 256 + t] = kvsrc4[i * 256 + t];
        kvs4[i * 256 + t] = kvsrc4[1024 + i * 256 + t];
    }
    if (t < 64) sidx[t] = selidx[(size_t)bh * NS_ + blockIdx.x * 64 + t];
    __syncthreads();

    // gather 64 q rows: 4 independent float4 loads per thread
#pragma unroll
    for (int c = 0; c < 4; ++c) {
        int i = c * 256 + t;
        int row = i >> 4, qp = i & 15;
        int sr = sidx[row];
        *(float4*)&qs[row * 68 + qp * 4] =
            *(const float4*)(q32 + (size_t)(b * S_ + sr) * E_ + h * 64 + qp * 4);
    }
    __syncthreads();

    int tok = t >> 2, eq = t & 3;          // token row, e-quarter (16 e each)
    int sr = sidx[tok];
    float th = (float)sr * THSTEP;
    float cw = __cosf(th), sw = __sinf(th);

    f32x2 acc2[8];
#pragma unroll
    for (int e = 0; e < 8; e++) acc2[e] = (f32x2){0.f, 0.f};

    const float4* kvcb = (const float4*)&kvc[eq * 16];
    const float4* kvsb = (const float4*)&kvs[eq * 16];
    for (int d = 0; d < 64; ++d) {
        float qd = fmaxf(qs[tok * 68 + d], 0.f);
        f32x2 a2 = { qd * cw, qd * cw };
        f32x2 b2 = { qd * sw, qd * sw };
#pragma unroll
        for (int c = 0; c < 4; ++c) {
            float4 c4 = kvcb[d * 16 + c];
            float4 s4 = kvsb[d * 16 + c];
            f32x2 c01 = { c4.x, c4.y }, c23 = { c4.z, c4.w };
            f32x2 s01 = { s4.x, s4.y }, s23 = { s4.z, s4.w };
            acc2[c * 2 + 0] += a2 * c01 + b2 * s01;
            acc2[c * 2 + 1] += a2 * c23 + b2 * s23;
        }
    }

    float* dst = out + (size_t)(b * S_ + sr) * E_ + h * 64 + eq * 16;
#pragma unroll
    for (int c = 0; c < 4; ++c) {
        float4 o = { acc2[c * 2 + 0][0], acc2[c * 2 + 0][1],
                     acc2[c * 2 + 1][0], acc2[c * 2 + 1][1] };
        *(float4*)(dst + c * 4) = o;
    }
}

extern "C" void kernel_launch(void* const* d_in, const int* in_sizes, int n_in,
                              void* d_out, int out_size, void* d_ws, size_t ws_size,
                              hipStream_t stream)
{
    const float* x  = (const float*)d_in[0];
    const float* Wq = (const float*)d_in[1];
    const float* bq = (const float*)d_in[2];
    const float* Wk = (const float*)d_in[3];
    const float* bk = (const float*)d_in[4];
    const float* Wv = (const float*)d_in[5];
    const float* bv = (const float*)d_in[6];

    char* ws = (char*)d_ws;
    ushort* xh     = (ushort*)(ws);                   // 33,554,432 B
    float*  kvp    = (float*)(ws);                    // aliases xh (dead after GEMM)
    float*  q32    = (float*)(ws + 33554432);         // 67,108,864 B
    float*  k32    = (float*)(ws + 100663296);        // 67,108,864 B
    ushort* v16    = (ushort*)(ws + 167772160);       // 33,554,432 B
    ushort* Wqh    = (ushort*)(ws + 201326592);       //  2,097,152 B
    ushort* Wql    = (ushort*)(ws + 203423744);
    ushort* Wkh    = (ushort*)(ws + 205520896);
    ushort* Wkl    = (ushort*)(ws + 207618048);
    ushort* Wvh    = (ushort*)(ws + 209715200);
    float*  scores = (float*)(ws + 211812352);        //  1,048,576 B
    int*    selidx = (int*)(ws + 212860928);          //    262,144 B
    int*    band   = (int*)(ws + 213123072);          //     24,576 B
    double* bscore = (double*)(ws + 213147648);       //     49,152 B
    int*    meta   = (int*)(ws + 213196800);          //        512 B
    float*  kv     = (float*)(ws + 213197312);        //  2,097,152 B (end ~205.3 MiB)
    float*  out    = (float*)d_out;

    hipLaunchKernelGGL(prep_kernel, dim3(4096), dim3(256), 0, stream,
                       x, Wq, Wk, Wv, xh, Wqh, Wql, Wkh, Wkl, Wvh, (uint4*)out);
    hipLaunchKernelGGL((qkv_gemm_t<1>), dim3(128, 8), dim3(256), 0, stream,
                       xh, Wqh, Wql, bq, q32, (ushort*)nullptr);
    hipLaunchKernelGGL((qkv_gemm_t<1>), dim3(128, 8), dim3(256), 0, stream,
                       xh, Wkh, Wkl, bk, k32, (ushort*)nullptr);
    hipLaunchKernelGGL((qkv_gemm_t<0>), dim3(128, 8), dim3(256), 0, stream,
                       xh, Wvh, Wvh, bv, (float*)nullptr, v16);
    hipLaunchKernelGGL(scores_kernel, dim3((B_ * H_ * S_) / 16), dim3(256), 0, stream,
                       q32, k32, scores);
    hipLaunchKernelGGL(band_select_kernel, dim3(B_ * H_), dim3(256), 0, stream,
                       scores, selidx, band, meta);
    hipLaunchKernelGGL(band_exact_kernel, dim3(BANDCAP, B_ * H_), dim3(512), 0, stream,
                       x, Wq, Wk, band, meta, bscore);
    hipLaunchKernelGGL(band_rank_kernel, dim3(B_ * H_), dim3(128), 0, stream,
                       bscore, band, meta, selidx);
    hipLaunchKernelGGL(kv_partial_kernel, dim3(16, 64), dim3(256), 0, stream,
                       k32, v16, kvp);
    hipLaunchKernelGGL(kv_reduce_kernel, dim3(2048), dim3(256), 0, stream,
                       kvp, kv);
    hipLaunchKernelGGL(sampled_kernel, dim3(NS_ / 64, B_ * H_), dim3(256), 0, stream,
                       q32, selidx, kv, out);
}

// Round 4
// 509.774 us; speedup vs baseline: 1.1377x; 1.1377x over previous
//
#include <hip/hip_runtime.h>
#include <hip/hip_bf16.h>

#define B_ 4
#define S_ 4096
#define E_ 1024
#define H_ 16
#define D_ 64
#define NS_ 1024
#define M_ (B_*S_)
#define K_ E_
#define DELTA 0.12f
#define BANDCAP 96

typedef __attribute__((ext_vector_type(8))) short bf16x8;
typedef __attribute__((ext_vector_type(4))) float floatx4;

#define THSTEP 0.00038349519697141023f  /* (pi/2)/4096 */

__device__ inline float bf16_to_f(unsigned short u) {
    return __uint_as_float(((unsigned)u) << 16);
}
__device__ inline unsigned short f_to_bf16(float f) {
    unsigned u = __float_as_uint(f);
    unsigned r = (u + 0x7FFFu + ((u >> 16) & 1u)) >> 16;  // RNE
    return (unsigned short)r;
}

// async global->LDS DMA, 16B per lane, wave-uniform LDS base + lane*16 dest.
__device__ inline void gl_lds16(const void* g, void* l) {
    __builtin_amdgcn_global_load_lds(
        (const __attribute__((address_space(1))) void*)g,
        (__attribute__((address_space(3))) void*)l, 16, 0, 0);
}

// ---------------------------------------------------------------------------
// Split pass 1: x (fp32) -> xh (bf16 round)
// ---------------------------------------------------------------------------
__global__ __launch_bounds__(256) void split_x_kernel(
    const float* __restrict__ x, ushort* __restrict__ xh)
{
    int i = blockIdx.x * 256 + threadIdx.x;          // over float4s, exact grid
    float4 v = ((const float4*)x)[i];
    ushort4 hh;
    hh.x = f_to_bf16(v.x); hh.y = f_to_bf16(v.y);
    hh.z = f_to_bf16(v.z); hh.w = f_to_bf16(v.w);
    ((ushort4*)xh)[i] = hh;
}

// Split pass 2: Wq,Wk -> hi+lo bf16; Wv -> hi only
__global__ __launch_bounds__(256) void split_w_kernel(
    const float* __restrict__ Wq, const float* __restrict__ Wk,
    const float* __restrict__ Wv,
    ushort* __restrict__ Wqh, ushort* __restrict__ Wql,
    ushort* __restrict__ Wkh, ushort* __restrict__ Wkl,
    ushort* __restrict__ Wvh)
{
    int i = blockIdx.x * 256 + threadIdx.x;          // over float4s, exact grid
    float4 q = ((const float4*)Wq)[i];
    float4 k = ((const float4*)Wk)[i];
    float4 v = ((const float4*)Wv)[i];
    ushort4 h, l;
    h.x=f_to_bf16(q.x); l.x=f_to_bf16(q.x-bf16_to_f(h.x));
    h.y=f_to_bf16(q.y); l.y=f_to_bf16(q.y-bf16_to_f(h.y));
    h.z=f_to_bf16(q.z); l.z=f_to_bf16(q.z-bf16_to_f(h.z));
    h.w=f_to_bf16(q.w); l.w=f_to_bf16(q.w-bf16_to_f(h.w));
    ((ushort4*)Wqh)[i]=h; ((ushort4*)Wql)[i]=l;
    h.x=f_to_bf16(k.x); l.x=f_to_bf16(k.x-bf16_to_f(h.x));
    h.y=f_to_bf16(k.y); l.y=f_to_bf16(k.y-bf16_to_f(h.y));
    h.z=f_to_bf16(k.z); l.z=f_to_bf16(k.z-bf16_to_f(h.z));
    h.w=f_to_bf16(k.w); l.w=f_to_bf16(k.w-bf16_to_f(h.w));
    ((ushort4*)Wkh)[i]=h; ((ushort4*)Wkl)[i]=l;
    h.x=f_to_bf16(v.x); h.y=f_to_bf16(v.y);
    h.z=f_to_bf16(v.z); h.w=f_to_bf16(v.w);
    ((ushort4*)Wvh)[i]=h;
}

// ---------------------------------------------------------------------------
// Kernel 1: QKV GEMM (R1 form: merged z=3, global_load_lds, XCD-grouped grid)
// ---------------------------------------------------------------------------
__global__ __launch_bounds__(256) void qkv_gemm(
    const ushort* __restrict__ xh,
    const ushort* __restrict__ Wqh, const ushort* __restrict__ Wql,
    const ushort* __restrict__ Wkh, const ushort* __restrict__ Wkl,
    const ushort* __restrict__ Wvh,
    const float* __restrict__ bq, const float* __restrict__ bk,
    const float* __restrict__ bv,
    float* __restrict__ q32, float* __restrict__ k32, ushort* __restrict__ v16)
{
    __shared__ __align__(16) ushort As[128 * 64];
    __shared__ __align__(16) ushort Bsh[128 * 64];
    __shared__ __align__(16) ushort Bsl[128 * 64];

    const int w = blockIdx.z;
    const ushort* Bhp = (w == 0) ? Wqh : (w == 1) ? Wkh : Wvh;
    const ushort* Blp = (w == 0) ? Wql : Wkl;      // unused when w==2
    const float* bias = (w == 0) ? bq : (w == 1) ? bk : bv;
    const bool lo = (w < 2);

    const int m0 = blockIdx.x * 128;
    const int n0 = blockIdx.y * 128;
    const int t = threadIdx.x;
    const int wave = t >> 6, lane = t & 63;
    const int wm = (wave >> 1) * 64, wn = (wave & 1) * 64;
    const int m16 = lane & 15, quad = lane >> 4;

    floatx4 acc[4][4];
#pragma unroll
    for (int i = 0; i < 4; i++)
#pragma unroll
        for (int j = 0; j < 4; j++) acc[i][j] = (floatx4){0.f, 0.f, 0.f, 0.f};

    int aoff[4], boff[4], lbase[4];
#pragma unroll
    for (int i = 0; i < 4; i++) {
        int slot = i * 256 + t;
        int r = slot >> 3, c = slot & 7, g = c ^ (r & 7);
        aoff[i] = (m0 + r) * K_ + g * 8;
        boff[i] = (n0 + r) * K_ + g * 8;
        lbase[i] = (i * 256 + wave * 64) * 8;   // wave-uniform LDS element base
    }

    for (int ks = 0; ks < 16; ++ks) {
        const int kcol = ks * 64;
#pragma unroll
        for (int i = 0; i < 4; i++) {
            gl_lds16(xh + aoff[i] + kcol, &As[lbase[i]]);
            gl_lds16(Bhp + boff[i] + kcol, &Bsh[lbase[i]]);
        }
        if (lo) {
#pragma unroll
            for (int i = 0; i < 4; i++)
                gl_lds16(Blp + boff[i] + kcol, &Bsl[lbase[i]]);
        }
        __syncthreads();

#pragma unroll
        for (int kk = 0; kk < 2; ++kk) {
            bf16x8 af[4], bfr[4];
            const int g = kk * 4 + quad;
#pragma unroll
            for (int mt = 0; mt < 4; ++mt) {
                int r = wm + mt * 16 + m16;
                af[mt] = *(const bf16x8*)&As[(r * 8 + (g ^ (r & 7))) * 8];
            }
#pragma unroll
            for (int nt = 0; nt < 4; ++nt) {
                int r2 = wn + nt * 16 + m16;
                bfr[nt] = *(const bf16x8*)&Bsh[(r2 * 8 + (g ^ (r2 & 7))) * 8];
            }
#pragma unroll
            for (int mt = 0; mt < 4; ++mt)
#pragma unroll
                for (int nt = 0; nt < 4; ++nt)
                    acc[mt][nt] = __builtin_amdgcn_mfma_f32_16x16x32_bf16(
                        af[mt], bfr[nt], acc[mt][nt], 0, 0, 0);
            if (lo) {
#pragma unroll
                for (int nt = 0; nt < 4; ++nt) {
                    int r2 = wn + nt * 16 + m16;
                    bfr[nt] = *(const bf16x8*)&Bsl[(r2 * 8 + (g ^ (r2 & 7))) * 8];
                }
#pragma unroll
                for (int mt = 0; mt < 4; ++mt)
#pragma unroll
                    for (int nt = 0; nt < 4; ++nt)
                        acc[mt][nt] = __builtin_amdgcn_mfma_f32_16x16x32_bf16(
                            af[mt], bfr[nt], acc[mt][nt], 0, 0, 0);
            }
        }
        __syncthreads();
    }

    float biasv[4];
#pragma unroll
    for (int nt = 0; nt < 4; nt++)
        biasv[nt] = bias[n0 + wn + nt * 16 + m16];

    if (w < 2) {
        float* dst = (w == 0) ? q32 : k32;
#pragma unroll
        for (int mt = 0; mt < 4; ++mt)
#pragma unroll
            for (int nt = 0; nt < 4; ++nt) {
                int colg = n0 + wn + nt * 16 + m16;
#pragma unroll
                for (int reg = 0; reg < 4; ++reg) {
                    int rowg = m0 + wm + mt * 16 + quad * 4 + reg;
                    dst[(size_t)rowg * E_ + colg] = acc[mt][nt][reg] + biasv[nt];
                }
            }
    } else {
#pragma unroll
        for (int mt = 0; mt < 4; ++mt)
#pragma unroll
            for (int nt = 0; nt < 4; ++nt) {
                int colg = n0 + wn + nt * 16 + m16;
#pragma unroll
                for (int reg = 0; reg < 4; ++reg) {
                    int rowg = m0 + wm + mt * 16 + quad * 4 + reg;
                    v16[(size_t)rowg * E_ + colg] = f_to_bf16(acc[mt][nt][reg] + biasv[nt]);
                }
            }
    }
}

// ---------------------------------------------------------------------------
// Kernel 2: approx scores[b,h,s] = sum_d q*k (raw q,k fp32). one wave/token
// (R1 form)
// ---------------------------------------------------------------------------
__global__ __launch_bounds__(256) void scores_kernel(
    const float* __restrict__ q32, const float* __restrict__ k32,
    float* __restrict__ scores)
{
    int wid = blockIdx.x * 4 + (threadIdx.x >> 6);
    int lane = threadIdx.x & 63;
    int s = wid & (S_ - 1);
    int bh = wid >> 12;
    int b = bh >> 4, h = bh & 15;
    size_t addr = (size_t)(b * S_ + s) * E_ + h * 64 + lane;
    float p = q32[addr] * k32[addr];
#pragma unroll
    for (int m = 32; m; m >>= 1) p += __shfl_xor(p, m, 64);
    if (lane == 0) scores[wid] = p;
}

// ---------------------------------------------------------------------------
// Kernel 3: radix-select 1024th approx score T_a; classify into definite-in
// (> T_a+DELTA) and band (|score-T_a| <= DELTA).
// ---------------------------------------------------------------------------
__global__ __launch_bounds__(256) void band_select_kernel(
    const float* __restrict__ scores, int* __restrict__ selidx,
    int* __restrict__ band, int* __restrict__ meta)
{
    __shared__ unsigned keys[4096];
    __shared__ unsigned hist[256];
    __shared__ unsigned suf[256];
    __shared__ unsigned bcast[2];
    __shared__ int cnt_in, cnt_band;

    int bh = blockIdx.x;
    int t = threadIdx.x;
    const float* sc = scores + (size_t)bh * S_;

    for (int i = t; i < 4096; i += 256) {
        unsigned u = __float_as_uint(sc[i]);
        u = (u & 0x80000000u) ? ~u : (u | 0x80000000u);
        keys[i] = u;
    }
    if (t == 0) { cnt_in = 0; cnt_band = 0; }
    __syncthreads();

    unsigned prefix = 0, want = NS_;
    for (int shift = 24; shift >= 0; shift -= 8) {
        hist[t] = 0;
        __syncthreads();
        unsigned pmask = (shift == 24) ? 0u : (0xFFFFFFFFu << (shift + 8));
        for (int i = t; i < 4096; i += 256) {
            unsigned ky = keys[i];
            if ((ky & pmask) == prefix) atomicAdd(&hist[(ky >> shift) & 255u], 1u);
        }
        __syncthreads();
        suf[t] = hist[t];
        __syncthreads();
        for (int off = 1; off < 256; off <<= 1) {
            unsigned add = (t + off < 256) ? suf[t + off] : 0u;
            __syncthreads();
            suf[t] += add;
            __syncthreads();
        }
        unsigned Sb = suf[t];
        unsigned Snx = (t < 255) ? suf[t + 1] : 0u;
        if (Sb >= want && Snx < want) {          // unique t: S is decreasing
            bcast[0] = (unsigned)t;
            bcast[1] = want - Snx;
        }
        __syncthreads();
        prefix = prefix | (bcast[0] << shift);
        want = bcast[1];
        __syncthreads();
    }
    unsigned fb = (prefix & 0x80000000u) ? (prefix ^ 0x80000000u) : ~prefix;
    float Ta = __uint_as_float(fb);
    float Thi = Ta + DELTA, Tlo = Ta - DELTA;

    int* sel = selidx + (size_t)bh * NS_;
    int* bnd = band + (size_t)bh * BANDCAP;
    for (int i = t; i < 4096; i += 256) {
        float v = sc[i];
        if (v > Thi) {
            int p = atomicAdd(&cnt_in, 1);
            sel[p] = i;
        } else if (v >= Tlo) {
            int p = atomicAdd(&cnt_band, 1);
            if (p < BANDCAP) bnd[p] = i;
        }
    }
    __syncthreads();
    if (t == 0) {
        meta[bh * 2 + 0] = cnt_in;
        meta[bh * 2 + 1] = (cnt_band < BANDCAP) ? cnt_band : BANDCAP;
    }
}

// ---------------------------------------------------------------------------
// Kernel 4: exact fp64 band rescoring (R1 form)
// ---------------------------------------------------------------------------
__global__ __launch_bounds__(512) void band_exact_kernel(
    const float* __restrict__ x,
    const float* __restrict__ Wq, const float* __restrict__ Wk,
    const int* __restrict__ band, const int* __restrict__ meta,
    double* __restrict__ bscore)
{
    int j = blockIdx.x, bh = blockIdx.y;
    int NB = meta[bh * 2 + 1];
    if (j >= NB) return;
    int b = bh >> 4, h = bh & 15;
    int s = band[(size_t)bh * BANDCAP + j];
    int t = threadIdx.x;
    int wave = t >> 6, lane = t & 63;

    __shared__ float xs[1024];
    __shared__ double qkd[128];     // [0:64)=q dots, [64:128)=k dots

    if (t < 256)
        *(float4*)&xs[t * 4] = *(const float4*)(x + (size_t)(b * S_ + s) * K_ + t * 4);
    __syncthreads();

    // waves 0-3: Wq rows 16*wave.. | waves 4-7: Wk rows 16*(wave-4)..
    const float* Wbase = (wave < 4) ? Wq : Wk;
    int role = wave >> 2;
    int dbase = (wave & 3) * 16;
    const float4* xs4 = (const float4*)xs;

    for (int rr = 0; rr < 16; ++rr) {
        int d = dbase + rr;
        const float4* wrow4 = (const float4*)(Wbase + (size_t)(h * 64 + d) * K_);
        double a = 0.0;
#pragma unroll
        for (int p = 0; p < 4; ++p) {
            float4 wv = wrow4[lane + 64 * p];
            float4 xv = xs4[lane + 64 * p];
            a += (double)xv.x * wv.x + (double)xv.y * wv.y
               + (double)xv.z * wv.z + (double)xv.w * wv.w;
        }
#pragma unroll
        for (int m = 32; m; m >>= 1) a += __shfl_xor(a, m, 64);
        if (lane == 0) qkd[role * 64 + d] = a;
    }
    __syncthreads();

    if (t < 64) {
        double p = qkd[t] * qkd[64 + t];
#pragma unroll
        for (int m = 32; m; m >>= 1) p += __shfl_xor(p, m, 64);
        if (t == 0) bscore[(size_t)bh * BANDCAP + j] = p;
    }
}

// Kernel 5: rank band tokens (ties -> lower index), fill selidx positions.
__global__ __launch_bounds__(128) void band_rank_kernel(
    const double* __restrict__ bscore, const int* __restrict__ band,
    const int* __restrict__ meta, int* __restrict__ selidx)
{
    __shared__ double sc[BANDCAP];
    __shared__ int bi[BANDCAP];
    int bh = blockIdx.x, t = threadIdx.x;
    int cnt_in = meta[bh * 2 + 0], NB = meta[bh * 2 + 1];
    int need = NS_ - cnt_in;
    if (t < NB) {
        sc[t] = bscore[(size_t)bh * BANDCAP + t];
        bi[t] = band[(size_t)bh * BANDCAP + t];
    }
    __syncthreads();
    if (t < NB) {
        double mine = sc[t]; int myi = bi[t]; int r = 0;
        for (int j2 = 0; j2 < NB; ++j2)
            r += (sc[j2] > mine) || (sc[j2] == mine && bi[j2] < myi);
        if (r < need) selidx[(size_t)bh * NS_ + cnt_in + r] = myi;
    }
}

// ---------------------------------------------------------------------------
// Kernel 6 (R4 REWRITE): partial KV reductions via MFMA.
// kv[d][e] = sum_s relu(k[s,d])*cos_s * v[s,e]  (+ sin plane).
// Fold cos/sin into k: A-planes = {bf16hi, bf16lo} of relu(k)*cos and
// relu(k)*sin (hi+lo keeps fp32 precision); B = raw v16 bf16.
// Transpose s-major -> d-major via LDS (lane = s, wave = 16-d slice),
// row stride 88 ushorts (176B: 16B-aligned b128 frags, banks rotate).
// Each wave owns a 32x32 output quadrant -> no cross-wave reduction.
// grid (16 s-chunks, 64 bh) x 256 thr; writes kvp like before.
// ---------------------------------------------------------------------------
__global__ __launch_bounds__(256) void kv_mfma_kernel(
    const float* __restrict__ k32, const ushort* __restrict__ v16,
    float* __restrict__ kvp)
{
    // planes: 0 kc_hi, 1 kc_lo, 2 ks_hi, 3 ks_lo, 4 v   (each [64][88] ushort)
    __shared__ __align__(16) ushort P[5 * 64 * 88];

    const int ch = blockIdx.x;    // 0..15, 256 s each
    const int bh = blockIdx.y;    // 0..63
    const int b = bh >> 4, h = bh & 15;
    const int t = threadIdx.x;
    const int wave = t >> 6, lane = t & 63;
    const int m16 = lane & 15, quad = lane >> 4;
    const int wm = (wave >> 1) * 32, wn = (wave & 1) * 32;
    const int d0 = wave * 16;         // staging: this wave's d/e slice

    const float*  kbase = k32 + (size_t)b * S_ * E_ + h * 64 + d0;
    const ushort* vbase = v16 + (size_t)b * S_ * E_ + h * 64 + d0;

    floatx4 acc[2][2][2];             // [plane cos/sin][mt][nt]
#pragma unroll
    for (int p = 0; p < 2; p++)
#pragma unroll
        for (int i = 0; i < 2; i++)
#pragma unroll
            for (int j = 0; j < 2; j++) acc[p][i][j] = (floatx4){0.f,0.f,0.f,0.f};

    float  ka[16];
    ushort va[16];
    int sg = ch * 256 + lane;          // group-0 global s for this thread
    {
        const float*  kr = kbase + (size_t)sg * E_;
        const ushort* vr = vbase + (size_t)sg * E_;
#pragma unroll
        for (int j = 0; j < 4; ++j) *(float4*)&ka[j * 4] = ((const float4*)kr)[j];
        *(uint4*)&va[0] = *(const uint4*)vr;
        *(uint4*)&va[8] = *(const uint4*)(vr + 8);
    }

    for (int grp = 0; grp < 4; ++grp) {
        float th = (float)sg * THSTEP;
        float cw = __cosf(th), sw = __sinf(th);
        int s_loc = lane;

        __syncthreads();               // prev group's LDS fully consumed
#pragma unroll
        for (int j = 0; j < 16; ++j) {
            float kr_ = fmaxf(ka[j], 0.f);
            float pc = kr_ * cw, ps = kr_ * sw;
            ushort chh = f_to_bf16(pc);
            ushort cll = f_to_bf16(pc - bf16_to_f(chh));
            ushort shh = f_to_bf16(ps);
            ushort sll = f_to_bf16(ps - bf16_to_f(shh));
            int r = (d0 + j) * 88 + s_loc;
            P[0 * 5632 + r] = chh;
            P[1 * 5632 + r] = cll;
            P[2 * 5632 + r] = shh;
            P[3 * 5632 + r] = sll;
            P[4 * 5632 + r] = va[j];
        }
        __syncthreads();

        if (grp < 3) {                 // prefetch next group under the MFMAs
            sg += 64;
            const float*  kr = kbase + (size_t)sg * E_;
            const ushort* vr = vbase + (size_t)sg * E_;
#pragma unroll
            for (int j = 0; j < 4; ++j) *(float4*)&ka[j * 4] = ((const float4*)kr)[j];
            *(uint4*)&va[0] = *(const uint4*)vr;
            *(uint4*)&va[8] = *(const uint4*)(vr + 8);
        }

#pragma unroll
        for (int kk = 0; kk < 2; ++kk) {
            const int so = kk * 32 + quad * 8;
            bf16x8 ach[2], acl[2], ash[2], asl[2], bv[2];
#pragma unroll
            for (int mt = 0; mt < 2; ++mt) {
                int r = (wm + mt * 16 + m16) * 88 + so;
                ach[mt] = *(const bf16x8*)&P[0 * 5632 + r];
                acl[mt] = *(const bf16x8*)&P[1 * 5632 + r];
                ash[mt] = *(const bf16x8*)&P[2 * 5632 + r];
                asl[mt] = *(const bf16x8*)&P[3 * 5632 + r];
            }
#pragma unroll
            for (int nt = 0; nt < 2; ++nt) {
                int r = (wn + nt * 16 + m16) * 88 + so;
                bv[nt] = *(const bf16x8*)&P[4 * 5632 + r];
            }
#pragma unroll
            for (int mt = 0; mt < 2; ++mt)
#pragma unroll
                for (int nt = 0; nt < 2; ++nt) {
                    acc[0][mt][nt] = __builtin_amdgcn_mfma_f32_16x16x32_bf16(
                        ach[mt], bv[nt], acc[0][mt][nt], 0, 0, 0);
                    acc[0][mt][nt] = __builtin_amdgcn_mfma_f32_16x16x32_bf16(
                        acl[mt], bv[nt], acc[0][mt][nt], 0, 0, 0);
                    acc[1][mt][nt] = __builtin_amdgcn_mfma_f32_16x16x32_bf16(
                        ash[mt], bv[nt], acc[1][mt][nt], 0, 0, 0);
                    acc[1][mt][nt] = __builtin_amdgcn_mfma_f32_16x16x32_bf16(
                        asl[mt], bv[nt], acc[1][mt][nt], 0, 0, 0);
                }
        }
    }

    // write quadrant partials; C layout row = quad*4+reg, col = m16
    float* base = kvp + ((size_t)(bh * 16 + ch) * 2) * 4096;
#pragma unroll
    for (int p = 0; p < 2; ++p)
#pragma unroll
        for (int mt = 0; mt < 2; ++mt)
#pragma unroll
            for (int nt = 0; nt < 2; ++nt)
#pragma unroll
                for (int reg = 0; reg < 4; ++reg) {
                    int row = wm + mt * 16 + quad * 4 + reg;
                    int col = wn + nt * 16 + m16;
                    base[p * 4096 + row * 64 + col] = acc[p][mt][nt][reg];
                }
}

// Kernel 7: reduce the 16 partials -> kv[bh][{cos,sin}][64][64]
__global__ __launch_bounds__(256) void kv_reduce_kernel(
    const float* __restrict__ kvp, float* __restrict__ kv)
{
    int i = blockIdx.x * 256 + threadIdx.x;   // 0 .. 64*2*4096-1
    if (i >= 64 * 2 * 4096) return;
    int bh = i >> 13;
    int rem = i & 8191;
    const float* p = kvp + (size_t)bh * 16 * 8192 + rem;
    float a = 0.f;
#pragma unroll
    for (int c = 0; c < 16; c++) a += p[c * 8192];
    kv[i] = a;
}

// ---------------------------------------------------------------------------
// Kernel 8: sampled = qs_cos @ kv_cos + qs_sin @ kv_sin (R1 form)
// ---------------------------------------------------------------------------
__global__ __launch_bounds__(256) void sampled_kernel(
    const float* __restrict__ q32, const int* __restrict__ selidx,
    const float* __restrict__ kv, float* __restrict__ out)
{
    __shared__ float kvc[4096];
    __shared__ float kvs[4096];
    __shared__ float qs[256 * 65];
    __shared__ int sidx[256];
    int bh = blockIdx.y;
    int b = bh >> 4, h = bh & 15;
    int t = threadIdx.x;
    int wave = t >> 6, lane = t & 63;

    const float* kvsrc = kv + (size_t)bh * 8192;
    for (int i = t; i < 4096; i += 256) {
        kvc[i] = kvsrc[i];
        kvs[i] = kvsrc[4096 + i];
    }
    sidx[t] = selidx[(size_t)bh * NS_ + blockIdx.x * 256 + t];
    __syncthreads();

    // gather q rows, one row per wave-iteration (coalesced 256B loads)
    for (int i = 0; i < 64; ++i) {
        int row = wave * 64 + i;
        int sr = sidx[row];
        qs[row * 65 + lane] = q32[(size_t)(b * S_ + sr) * E_ + h * 64 + lane];
    }
    __syncthreads();

    int s = sidx[t];
    float th = (float)s * THSTEP;
    float cw = __cosf(th), sw = __sinf(th);

    float acc[64];
#pragma unroll
    for (int e = 0; e < 64; e++) acc[e] = 0.f;

    for (int d = 0; d < 64; ++d) {
        float qd = fmaxf(qs[t * 65 + d], 0.f);
        float a = qd * cw, bb = qd * sw;
        const float4* pc4 = (const float4*)&kvc[d * 64];
        const float4* ps4 = (const float4*)&kvs[d * 64];
#pragma unroll
        for (int e4 = 0; e4 < 16; e4++) {
            float4 c4 = pc4[e4], s4 = ps4[e4];
            acc[e4 * 4 + 0] += a * c4.x + bb * s4.x;
            acc[e4 * 4 + 1] += a * c4.y + bb * s4.y;
            acc[e4 * 4 + 2] += a * c4.z + bb * s4.z;
            acc[e4 * 4 + 3] += a * c4.w + bb * s4.w;
        }
    }
    __syncthreads();
#pragma unroll
    for (int e = 0; e < 64; e++) qs[t * 65 + e] = acc[e];
    __syncthreads();

    // scatter result rows, one row per wave-iteration (coalesced 256B stores)
    for (int i = 0; i < 64; ++i) {
        int row = wave * 64 + i;
        int sr = sidx[row];
        out[(size_t)(b * S_ + sr) * E_ + h * 64 + lane] = qs[row * 65 + lane];
    }
}

__global__ void zero_kernel(uint4* __restrict__ p, int n16)
{
    int stride = gridDim.x * blockDim.x;
    for (int i = blockIdx.x * blockDim.x + threadIdx.x; i < n16; i += stride)
        p[i] = make_uint4(0u, 0u, 0u, 0u);
}

extern "C" void kernel_launch(void* const* d_in, const int* in_sizes, int n_in,
                              void* d_out, int out_size, void* d_ws, size_t ws_size,
                              hipStream_t stream)
{
    const float* x  = (const float*)d_in[0];
    const float* Wq = (const float*)d_in[1];
    const float* bq = (const float*)d_in[2];
    const float* Wk = (const float*)d_in[3];
    const float* bk = (const float*)d_in[4];
    const float* Wv = (const float*)d_in[5];
    const float* bv = (const float*)d_in[6];

    char* ws = (char*)d_ws;
    ushort* xh     = (ushort*)(ws);                   // 33,554,432 B
    float*  kvp    = (float*)(ws);                    // aliases xh (dead after GEMM)
    float*  q32    = (float*)(ws + 33554432);         // 67,108,864 B
    float*  k32    = (float*)(ws + 100663296);        // 67,108,864 B
    ushort* v16    = (ushort*)(ws + 167772160);       // 33,554,432 B
    ushort* Wqh    = (ushort*)(ws + 201326592);       //  2,097,152 B
    ushort* Wql    = (ushort*)(ws + 203423744);
    ushort* Wkh    = (ushort*)(ws + 205520896);
    ushort* Wkl    = (ushort*)(ws + 207618048);
    ushort* Wvh    = (ushort*)(ws + 209715200);
    float*  scores = (float*)(ws + 211812352);        //  1,048,576 B
    int*    selidx = (int*)(ws + 212860928);          //    262,144 B
    int*    band   = (int*)(ws + 213123072);          //     24,576 B
    double* bscore = (double*)(ws + 213147648);       //     49,152 B
    int*    meta   = (int*)(ws + 213196800);          //        512 B
    float*  kv     = (float*)(ws + 213197312);        //  2,097,152 B (end ~205.3 MiB)
    float*  out    = (float*)d_out;

    hipLaunchKernelGGL(zero_kernel, dim3(2048), dim3(256), 0, stream,
                       (uint4*)out, (int)((size_t)M_ * E_ * 4 / 16));
    hipLaunchKernelGGL(split_x_kernel, dim3((M_ * K_) / 1024), dim3(256), 0, stream,
                       x, xh);
    hipLaunchKernelGGL(split_w_kernel, dim3((E_ * E_) / 1024), dim3(256), 0, stream,
                       Wq, Wk, Wv, Wqh, Wql, Wkh, Wkl, Wvh);
    hipLaunchKernelGGL(qkv_gemm, dim3(128, 8, 3), dim3(256), 0, stream,
                       xh, Wqh, Wql, Wkh, Wkl, Wvh, bq, bk, bv, q32, k32, v16);
    hipLaunchKernelGGL(scores_kernel, dim3((B_ * H_ * S_) / 4), dim3(256), 0, stream,
                       q32, k32, scores);
    hipLaunchKernelGGL(band_select_kernel, dim3(B_ * H_), dim3(256), 0, stream,
                       scores, selidx, band, meta);
    hipLaunchKernelGGL(band_exact_kernel, dim3(BANDCAP, B_ * H_), dim3(512), 0, stream,
                       x, Wq, Wk, band, meta, bscore);
    hipLaunchKernelGGL(band_rank_kernel, dim3(B_ * H_), dim3(128), 0, stream,
                       bscore, band, meta, selidx);
    hipLaunchKernelGGL(kv_mfma_kernel, dim3(16, 64), dim3(256), 0, stream,
                       k32, v16, kvp);
    hipLaunchKernelGGL(kv_reduce_kernel, dim3(2048), dim3(256), 0, stream,
                       kvp, kv);
    hipLaunchKernelGGL(sampled_kernel, dim3(NS_ / 256, B_ * H_), dim3(256), 0, stream,
                       q32, selidx, kv, out);
}

// Round 5
// 501.623 us; speedup vs baseline: 1.1562x; 1.0162x over previous
//
#include <hip/hip_runtime.h>
#include <hip/hip_bf16.h>

#define B_ 4
#define S_ 4096
#define E_ 1024
#define H_ 16
#define D_ 64
#define NS_ 1024
#define M_ (B_*S_)
#define K_ E_
#define DELTA 0.12f
#define BANDCAP 96

typedef __attribute__((ext_vector_type(8))) short bf16x8;
typedef __attribute__((ext_vector_type(4))) float floatx4;
typedef __attribute__((ext_vector_type(2))) float f32x2;

#define THSTEP 0.00038349519697141023f  /* (pi/2)/4096 */

__device__ inline float bf16_to_f(unsigned short u) {
    return __uint_as_float(((unsigned)u) << 16);
}
__device__ inline unsigned short f_to_bf16(float f) {
    unsigned u = __float_as_uint(f);
    unsigned r = (u + 0x7FFFu + ((u >> 16) & 1u)) >> 16;  // RNE
    return (unsigned short)r;
}

// async global->LDS DMA, 16B per lane, wave-uniform LDS base + lane*16 dest.
__device__ inline void gl_lds16(const void* g, void* l) {
    __builtin_amdgcn_global_load_lds(
        (const __attribute__((address_space(1))) void*)g,
        (__attribute__((address_space(3))) void*)l, 16, 0, 0);
}

// ---------------------------------------------------------------------------
// Prep kernel: fuses {zero(out), x->xh bf16, W splits}.  4096 blocks x 256.
// ---------------------------------------------------------------------------
__global__ __launch_bounds__(256) void prep_kernel(
    const float* __restrict__ x,
    const float* __restrict__ Wq, const float* __restrict__ Wk,
    const float* __restrict__ Wv,
    ushort* __restrict__ xh,
    ushort* __restrict__ Wqh, ushort* __restrict__ Wql,
    ushort* __restrict__ Wkh, ushort* __restrict__ Wkl,
    ushort* __restrict__ Wvh,
    uint4* __restrict__ outz)
{
    int t = blockIdx.x * 256 + threadIdx.x;     // 0 .. 1,048,575
    uint4 z = make_uint4(0u, 0u, 0u, 0u);
#pragma unroll
    for (int c = 0; c < 4; ++c)
        outz[c * 1048576 + t] = z;               // 4M uint4 = 64MB out
#pragma unroll
    for (int c = 0; c < 4; ++c) {
        int i = c * 1048576 + t;                 // 4M float4 of x
        float4 v = ((const float4*)x)[i];
        ushort4 hh;
        hh.x = f_to_bf16(v.x); hh.y = f_to_bf16(v.y);
        hh.z = f_to_bf16(v.z); hh.w = f_to_bf16(v.w);
        ((ushort4*)xh)[i] = hh;
    }
    if (t < 262144) {                            // 256K float4 per W matrix
        int i = t;
        float4 q = ((const float4*)Wq)[i];
        float4 k = ((const float4*)Wk)[i];
        float4 v = ((const float4*)Wv)[i];
        ushort4 h, l;
        h.x=f_to_bf16(q.x); l.x=f_to_bf16(q.x-bf16_to_f(h.x));
        h.y=f_to_bf16(q.y); l.y=f_to_bf16(q.y-bf16_to_f(h.y));
        h.z=f_to_bf16(q.z); l.z=f_to_bf16(q.z-bf16_to_f(h.z));
        h.w=f_to_bf16(q.w); l.w=f_to_bf16(q.w-bf16_to_f(h.w));
        ((ushort4*)Wqh)[i]=h; ((ushort4*)Wql)[i]=l;
        h.x=f_to_bf16(k.x); l.x=f_to_bf16(k.x-bf16_to_f(h.x));
        h.y=f_to_bf16(k.y); l.y=f_to_bf16(k.y-bf16_to_f(h.y));
        h.z=f_to_bf16(k.z); l.z=f_to_bf16(k.z-bf16_to_f(h.z));
        h.w=f_to_bf16(k.w); l.w=f_to_bf16(k.w-bf16_to_f(h.w));
        ((ushort4*)Wkh)[i]=h; ((ushort4*)Wkl)[i]=l;
        h.x=f_to_bf16(v.x); h.y=f_to_bf16(v.y);
        h.z=f_to_bf16(v.z); h.w=f_to_bf16(v.w);
        ((ushort4*)Wvh)[i]=h;
    }
}

// ---------------------------------------------------------------------------
// Kernel 1: QKV GEMM (merged z=3, global_load_lds, XCD-grouped grid) —
// stable optimum for this structure; do not split (R3: +30 µs).
// ---------------------------------------------------------------------------
__global__ __launch_bounds__(256) void qkv_gemm(
    const ushort* __restrict__ xh,
    const ushort* __restrict__ Wqh, const ushort* __restrict__ Wql,
    const ushort* __restrict__ Wkh, const ushort* __restrict__ Wkl,
    const ushort* __restrict__ Wvh,
    const float* __restrict__ bq, const float* __restrict__ bk,
    const float* __restrict__ bv,
    float* __restrict__ q32, float* __restrict__ k32, ushort* __restrict__ v16)
{
    __shared__ __align__(16) ushort As[128 * 64];
    __shared__ __align__(16) ushort Bsh[128 * 64];
    __shared__ __align__(16) ushort Bsl[128 * 64];

    const int w = blockIdx.z;
    const ushort* Bhp = (w == 0) ? Wqh : (w == 1) ? Wkh : Wvh;
    const ushort* Blp = (w == 0) ? Wql : Wkl;      // unused when w==2
    const float* bias = (w == 0) ? bq : (w == 1) ? bk : bv;
    const bool lo = (w < 2);

    const int m0 = blockIdx.x * 128;
    const int n0 = blockIdx.y * 128;
    const int t = threadIdx.x;
    const int wave = t >> 6, lane = t & 63;
    const int wm = (wave >> 1) * 64, wn = (wave & 1) * 64;
    const int m16 = lane & 15, quad = lane >> 4;

    floatx4 acc[4][4];
#pragma unroll
    for (int i = 0; i < 4; i++)
#pragma unroll
        for (int j = 0; j < 4; j++) acc[i][j] = (floatx4){0.f, 0.f, 0.f, 0.f};

    int aoff[4], boff[4], lbase[4];
#pragma unroll
    for (int i = 0; i < 4; i++) {
        int slot = i * 256 + t;
        int r = slot >> 3, c = slot & 7, g = c ^ (r & 7);
        aoff[i] = (m0 + r) * K_ + g * 8;
        boff[i] = (n0 + r) * K_ + g * 8;
        lbase[i] = (i * 256 + wave * 64) * 8;   // wave-uniform LDS element base
    }

    for (int ks = 0; ks < 16; ++ks) {
        const int kcol = ks * 64;
#pragma unroll
        for (int i = 0; i < 4; i++) {
            gl_lds16(xh + aoff[i] + kcol, &As[lbase[i]]);
            gl_lds16(Bhp + boff[i] + kcol, &Bsh[lbase[i]]);
        }
        if (lo) {
#pragma unroll
            for (int i = 0; i < 4; i++)
                gl_lds16(Blp + boff[i] + kcol, &Bsl[lbase[i]]);
        }
        __syncthreads();

#pragma unroll
        for (int kk = 0; kk < 2; ++kk) {
            bf16x8 af[4], bfr[4];
            const int g = kk * 4 + quad;
#pragma unroll
            for (int mt = 0; mt < 4; ++mt) {
                int r = wm + mt * 16 + m16;
                af[mt] = *(const bf16x8*)&As[(r * 8 + (g ^ (r & 7))) * 8];
            }
#pragma unroll
            for (int nt = 0; nt < 4; ++nt) {
                int r2 = wn + nt * 16 + m16;
                bfr[nt] = *(const bf16x8*)&Bsh[(r2 * 8 + (g ^ (r2 & 7))) * 8];
            }
#pragma unroll
            for (int mt = 0; mt < 4; ++mt)
#pragma unroll
                for (int nt = 0; nt < 4; ++nt)
                    acc[mt][nt] = __builtin_amdgcn_mfma_f32_16x16x32_bf16(
                        af[mt], bfr[nt], acc[mt][nt], 0, 0, 0);
            if (lo) {
#pragma unroll
                for (int nt = 0; nt < 4; ++nt) {
                    int r2 = wn + nt * 16 + m16;
                    bfr[nt] = *(const bf16x8*)&Bsl[(r2 * 8 + (g ^ (r2 & 7))) * 8];
                }
#pragma unroll
                for (int mt = 0; mt < 4; ++mt)
#pragma unroll
                    for (int nt = 0; nt < 4; ++nt)
                        acc[mt][nt] = __builtin_amdgcn_mfma_f32_16x16x32_bf16(
                            af[mt], bfr[nt], acc[mt][nt], 0, 0, 0);
            }
        }
        __syncthreads();
    }

    float biasv[4];
#pragma unroll
    for (int nt = 0; nt < 4; nt++)
        biasv[nt] = bias[n0 + wn + nt * 16 + m16];

    if (w < 2) {
        float* dst = (w == 0) ? q32 : k32;
#pragma unroll
        for (int mt = 0; mt < 4; ++mt)
#pragma unroll
            for (int nt = 0; nt < 4; ++nt) {
                int colg = n0 + wn + nt * 16 + m16;
#pragma unroll
                for (int reg = 0; reg < 4; ++reg) {
                    int rowg = m0 + wm + mt * 16 + quad * 4 + reg;
                    dst[(size_t)rowg * E_ + colg] = acc[mt][nt][reg] + biasv[nt];
                }
            }
    } else {
#pragma unroll
        for (int mt = 0; mt < 4; ++mt)
#pragma unroll
            for (int nt = 0; nt < 4; ++nt) {
                int colg = n0 + wn + nt * 16 + m16;
#pragma unroll
                for (int reg = 0; reg < 4; ++reg) {
                    int rowg = m0 + wm + mt * 16 + quad * 4 + reg;
                    v16[(size_t)rowg * E_ + colg] = f_to_bf16(acc[mt][nt][reg] + biasv[nt]);
                }
            }
    }
}

// ---------------------------------------------------------------------------
// Kernel 2: scores[b,h,s] = sum_d q*k.  float4/lane, one token per 16-lane
// group (R2-proven form).
// ---------------------------------------------------------------------------
__global__ __launch_bounds__(256) void scores_kernel(
    const float* __restrict__ q32, const float* __restrict__ k32,
    float* __restrict__ scores)
{
    int g = blockIdx.x * 16 + (threadIdx.x >> 4);    // token slot == (bh<<12)|s
    int sub = threadIdx.x & 15;
    int s = g & (S_ - 1);
    int bh = g >> 12;
    int b = bh >> 4, h = bh & 15;
    size_t addr = (size_t)(b * S_ + s) * E_ + h * 64 + sub * 4;
    float4 qv = *(const float4*)(q32 + addr);
    float4 kv = *(const float4*)(k32 + addr);
    float p = qv.x * kv.x + qv.y * kv.y + qv.z * kv.z + qv.w * kv.w;
#pragma unroll
    for (int m = 8; m; m >>= 1) p += __shfl_xor(p, m, 64);  // within 16-lane group
    if (sub == 0) scores[g] = p;
}

// ---------------------------------------------------------------------------
// Kernel 3: radix-select 1024th approx score T_a.  R5: Hillis-Steele LDS scan
// (8 steps x 2 barriers) replaced by wave shfl_down suffix scan + 4-entry
// cross-wave combine: 19 -> 4 barriers per pass, identical suffix sums.
// ---------------------------------------------------------------------------
__global__ __launch_bounds__(256) void band_select_kernel(
    const float* __restrict__ scores, int* __restrict__ selidx,
    int* __restrict__ band, int* __restrict__ meta)
{
    __shared__ unsigned keys[4096];
    __shared__ unsigned hist[256];
    __shared__ unsigned wtot[4];
    __shared__ unsigned bcast[2];
    __shared__ int cnt_in, cnt_band;

    int bh = blockIdx.x;
    int t = threadIdx.x;
    int wave = t >> 6, lane = t & 63;
    const float* sc = scores + (size_t)bh * S_;

    for (int i = t; i < 4096; i += 256) {
        unsigned u = __float_as_uint(sc[i]);
        u = (u & 0x80000000u) ? ~u : (u | 0x80000000u);
        keys[i] = u;
    }
    if (t == 0) { cnt_in = 0; cnt_band = 0; }

    unsigned prefix = 0, want = NS_;
    for (int shift = 24; shift >= 0; shift -= 8) {
        hist[t] = 0;
        __syncthreads();
        unsigned pmask = (shift == 24) ? 0u : (0xFFFFFFFFu << (shift + 8));
        for (int i = t; i < 4096; i += 256) {
            unsigned ky = keys[i];
            if ((ky & pmask) == prefix) atomicAdd(&hist[(ky >> shift) & 255u], 1u);
        }
        __syncthreads();
        // wave-level suffix scan: sv = sum over bins [t .. wave_end]
        unsigned sv = hist[t];
#pragma unroll
        for (int off = 1; off < 64; off <<= 1) {
            unsigned o = __shfl_down(sv, off, 64);
            sv += (lane + off < 64) ? o : 0u;
        }
        if (lane == 0) wtot[wave] = sv;          // wave total
        __syncthreads();
        unsigned cross = 0;
#pragma unroll
        for (int w2 = 0; w2 < 4; ++w2)
            cross += (w2 > wave) ? wtot[w2] : 0u;
        unsigned Sb = sv + cross;                // suf[t]
        unsigned sv1 = __shfl_down(sv, 1, 64);
        unsigned Snx = (lane < 63) ? sv1 + cross : cross;   // suf[t+1] (0 at t=255)
        if (Sb >= want && Snx < want) {          // unique t: suf is decreasing
            bcast[0] = (unsigned)t;
            bcast[1] = want - Snx;
        }
        __syncthreads();
        prefix = prefix | (bcast[0] << shift);
        want = bcast[1];
        __syncthreads();
    }
    unsigned fb = (prefix & 0x80000000u) ? (prefix ^ 0x80000000u) : ~prefix;
    float Ta = __uint_as_float(fb);
    float Thi = Ta + DELTA, Tlo = Ta - DELTA;

    int* sel = selidx + (size_t)bh * NS_;
    int* bnd = band + (size_t)bh * BANDCAP;
    for (int i = t; i < 4096; i += 256) {
        float v = sc[i];
        if (v > Thi) {
            int p = atomicAdd(&cnt_in, 1);
            sel[p] = i;
        } else if (v >= Tlo) {
            int p = atomicAdd(&cnt_band, 1);
            if (p < BANDCAP) bnd[p] = i;
        }
    }
    __syncthreads();
    if (t == 0) {
        meta[bh * 2 + 0] = cnt_in;
        meta[bh * 2 + 1] = (cnt_band < BANDCAP) ? cnt_band : BANDCAP;
    }
}

// ---------------------------------------------------------------------------
// Kernel 4: exact fp64 band rescoring, 4 independent fp64 accumulators
// (R2-proven form).
// ---------------------------------------------------------------------------
__global__ __launch_bounds__(512) void band_exact_kernel(
    const float* __restrict__ x,
    const float* __restrict__ Wq, const float* __restrict__ Wk,
    const int* __restrict__ band, const int* __restrict__ meta,
    double* __restrict__ bscore)
{
    int j = blockIdx.x, bh = blockIdx.y;
    int NB = meta[bh * 2 + 1];
    if (j >= NB) return;
    int b = bh >> 4, h = bh & 15;
    int s = band[(size_t)bh * BANDCAP + j];
    int t = threadIdx.x;
    int wave = t >> 6, lane = t & 63;

    __shared__ float xs[1024];
    __shared__ double qkd[128];     // [0:64)=q dots, [64:128)=k dots

    if (t < 256)
        *(float4*)&xs[t * 4] = *(const float4*)(x + (size_t)(b * S_ + s) * K_ + t * 4);
    __syncthreads();

    const float* Wbase = (wave < 4) ? Wq : Wk;
    int role = wave >> 2;
    int dbase = (wave & 3) * 16;
    const float4* xs4 = (const float4*)xs;

    for (int rr = 0; rr < 16; ++rr) {
        int d = dbase + rr;
        const float4* wrow4 = (const float4*)(Wbase + (size_t)(h * 64 + d) * K_);
        double a0 = 0.0, a1 = 0.0, a2 = 0.0, a3 = 0.0;
#pragma unroll
        for (int p = 0; p < 4; ++p) {
            float4 wv = wrow4[lane + 64 * p];
            float4 xv = xs4[lane + 64 * p];
            a0 += (double)xv.x * wv.x;
            a1 += (double)xv.y * wv.y;
            a2 += (double)xv.z * wv.z;
            a3 += (double)xv.w * wv.w;
        }
        double a = (a0 + a1) + (a2 + a3);
#pragma unroll
        for (int m = 32; m; m >>= 1) a += __shfl_xor(a, m, 64);
        if (lane == 0) qkd[role * 64 + d] = a;
    }
    __syncthreads();

    if (t < 64) {
        double p = qkd[t] * qkd[64 + t];
#pragma unroll
        for (int m = 32; m; m >>= 1) p += __shfl_xor(p, m, 64);
        if (t == 0) bscore[(size_t)bh * BANDCAP + j] = p;
    }
}

// Kernel 5: rank band tokens (ties -> lower index), fill selidx positions.
__global__ __launch_bounds__(128) void band_rank_kernel(
    const double* __restrict__ bscore, const int* __restrict__ band,
    const int* __restrict__ meta, int* __restrict__ selidx)
{
    __shared__ double sc[BANDCAP];
    __shared__ int bi[BANDCAP];
    int bh = blockIdx.x, t = threadIdx.x;
    int cnt_in = meta[bh * 2 + 0], NB = meta[bh * 2 + 1];
    int need = NS_ - cnt_in;
    if (t < NB) {
        sc[t] = bscore[(size_t)bh * BANDCAP + t];
        bi[t] = band[(size_t)bh * BANDCAP + t];
    }
    __syncthreads();
    if (t < NB) {
        double mine = sc[t]; int myi = bi[t]; int r = 0;
        for (int j2 = 0; j2 < NB; ++j2)
            r += (sc[j2] > mine) || (sc[j2] == mine && bi[j2] < myi);
        if (r < need) selidx[(size_t)bh * NS_ + cnt_in + r] = myi;
    }
}

// ---------------------------------------------------------------------------
// Kernel 6: partial KV reductions via MFMA (R4-proven form).
// ---------------------------------------------------------------------------
__global__ __launch_bounds__(256) void kv_mfma_kernel(
    const float* __restrict__ k32, const ushort* __restrict__ v16,
    float* __restrict__ kvp)
{
    // planes: 0 kc_hi, 1 kc_lo, 2 ks_hi, 3 ks_lo, 4 v   (each [64][88] ushort)
    __shared__ __align__(16) ushort P[5 * 64 * 88];

    const int ch = blockIdx.x;    // 0..15, 256 s each
    const int bh = blockIdx.y;    // 0..63
    const int b = bh >> 4, h = bh & 15;
    const int t = threadIdx.x;
    const int wave = t >> 6, lane = t & 63;
    const int m16 = lane & 15, quad = lane >> 4;
    const int wm = (wave >> 1) * 32, wn = (wave & 1) * 32;
    const int d0 = wave * 16;         // staging: this wave's d/e slice

    const float*  kbase = k32 + (size_t)b * S_ * E_ + h * 64 + d0;
    const ushort* vbase = v16 + (size_t)b * S_ * E_ + h * 64 + d0;

    floatx4 acc[2][2][2];             // [plane cos/sin][mt][nt]
#pragma unroll
    for (int p = 0; p < 2; p++)
#pragma unroll
        for (int i = 0; i < 2; i++)
#pragma unroll
            for (int j = 0; j < 2; j++) acc[p][i][j] = (floatx4){0.f,0.f,0.f,0.f};

    float  ka[16];
    ushort va[16];
    int sg = ch * 256 + lane;          // group-0 global s for this thread
    {
        const float*  kr = kbase + (size_t)sg * E_;
        const ushort* vr = vbase + (size_t)sg * E_;
#pragma unroll
        for (int j = 0; j < 4; ++j) *(float4*)&ka[j * 4] = ((const float4*)kr)[j];
        *(uint4*)&va[0] = *(const uint4*)vr;
        *(uint4*)&va[8] = *(const uint4*)(vr + 8);
    }

    for (int grp = 0; grp < 4; ++grp) {
        float th = (float)sg * THSTEP;
        float cw = __cosf(th), sw = __sinf(th);
        int s_loc = lane;

        __syncthreads();               // prev group's LDS fully consumed
#pragma unroll
        for (int j = 0; j < 16; ++j) {
            float kr_ = fmaxf(ka[j], 0.f);
            float pc = kr_ * cw, ps = kr_ * sw;
            ushort chh = f_to_bf16(pc);
            ushort cll = f_to_bf16(pc - bf16_to_f(chh));
            ushort shh = f_to_bf16(ps);
            ushort sll = f_to_bf16(ps - bf16_to_f(shh));
            int r = (d0 + j) * 88 + s_loc;
            P[0 * 5632 + r] = chh;
            P[1 * 5632 + r] = cll;
            P[2 * 5632 + r] = shh;
            P[3 * 5632 + r] = sll;
            P[4 * 5632 + r] = va[j];
        }
        __syncthreads();

        if (grp < 3) {                 // prefetch next group under the MFMAs
            sg += 64;
            const float*  kr = kbase + (size_t)sg * E_;
            const ushort* vr = vbase + (size_t)sg * E_;
#pragma unroll
            for (int j = 0; j < 4; ++j) *(float4*)&ka[j * 4] = ((const float4*)kr)[j];
            *(uint4*)&va[0] = *(const uint4*)vr;
            *(uint4*)&va[8] = *(const uint4*)(vr + 8);
        }

#pragma unroll
        for (int kk = 0; kk < 2; ++kk) {
            const int so = kk * 32 + quad * 8;
            bf16x8 ach[2], acl[2], ash[2], asl[2], bv[2];
#pragma unroll
            for (int mt = 0; mt < 2; ++mt) {
                int r = (wm + mt * 16 + m16) * 88 + so;
                ach[mt] = *(const bf16x8*)&P[0 * 5632 + r];
                acl[mt] = *(const bf16x8*)&P[1 * 5632 + r];
                ash[mt] = *(const bf16x8*)&P[2 * 5632 + r];
                asl[mt] = *(const bf16x8*)&P[3 * 5632 + r];
            }
#pragma unroll
            for (int nt = 0; nt < 2; ++nt) {
                int r = (wn + nt * 16 + m16) * 88 + so;
                bv[nt] = *(const bf16x8*)&P[4 * 5632 + r];
            }
#pragma unroll
            for (int mt = 0; mt < 2; ++mt)
#pragma unroll
                for (int nt = 0; nt < 2; ++nt) {
                    acc[0][mt][nt] = __builtin_amdgcn_mfma_f32_16x16x32_bf16(
                        ach[mt], bv[nt], acc[0][mt][nt], 0, 0, 0);
                    acc[0][mt][nt] = __builtin_amdgcn_mfma_f32_16x16x32_bf16(
                        acl[mt], bv[nt], acc[0][mt][nt], 0, 0, 0);
                    acc[1][mt][nt] = __builtin_amdgcn_mfma_f32_16x16x32_bf16(
                        ash[mt], bv[nt], acc[1][mt][nt], 0, 0, 0);
                    acc[1][mt][nt] = __builtin_amdgcn_mfma_f32_16x16x32_bf16(
                        asl[mt], bv[nt], acc[1][mt][nt], 0, 0, 0);
                }
        }
    }

    // write quadrant partials; C layout row = quad*4+reg, col = m16
    float* base = kvp + ((size_t)(bh * 16 + ch) * 2) * 4096;
#pragma unroll
    for (int p = 0; p < 2; ++p)
#pragma unroll
        for (int mt = 0; mt < 2; ++mt)
#pragma unroll
            for (int nt = 0; nt < 2; ++nt)
#pragma unroll
                for (int reg = 0; reg < 4; ++reg) {
                    int row = wm + mt * 16 + quad * 4 + reg;
                    int col = wn + nt * 16 + m16;
                    base[p * 4096 + row * 64 + col] = acc[p][mt][nt][reg];
                }
}

// Kernel 7: reduce the 16 partials -> kv[bh][{cos,sin}][64][64]
__global__ __launch_bounds__(256) void kv_reduce_kernel(
    const float* __restrict__ kvp, float* __restrict__ kv)
{
    int i = blockIdx.x * 256 + threadIdx.x;   // 0 .. 64*2*4096-1
    if (i >= 64 * 2 * 4096) return;
    int bh = i >> 13;
    int rem = i & 8191;
    const float* p = kvp + (size_t)bh * 16 * 8192 + rem;
    float a = 0.f;
#pragma unroll
    for (int c = 0; c < 16; c++) a += p[c * 8192];
    kv[i] = a;
}

// ---------------------------------------------------------------------------
// Kernel 8: sampled = qs_cos @ kv_cos + qs_sin @ kv_sin, scattered to out.
// (R2-proven form: grid (16,64), parallel gather, direct stores.)
// ---------------------------------------------------------------------------
__global__ __launch_bounds__(256) void sampled_kernel(
    const float* __restrict__ q32, const int* __restrict__ selidx,
    const float* __restrict__ kv, float* __restrict__ out)
{
    __shared__ __align__(16) float kvc[4096];
    __shared__ __align__(16) float kvs[4096];
    __shared__ __align__(16) float qs[64 * 68];   // stride 68: 16B-aligned rows
    __shared__ int sidx[64];
    int bh = blockIdx.y;
    int b = bh >> 4, h = bh & 15;
    int t = threadIdx.x;

    const float4* kvsrc4 = (const float4*)(kv + (size_t)bh * 8192);
    float4* kvc4 = (float4*)kvc;
    float4* kvs4 = (float4*)kvs;
#pragma unroll
    for (int i = 0; i < 4; ++i) {
        kvc4[i * 256 + t] = kvsrc4[i * 256 + t];
        kvs4[i * 256 + t] = kvsrc4[1024 + i * 256 + t];
    }
    if (t < 64) sidx[t] = selidx[(size_t)bh * NS_ + blockIdx.x * 64 + t];
    __syncthreads();

    // gather 64 q rows: 4 independent float4 loads per thread
#pragma unroll
    for (int c = 0; c < 4; ++c) {
        int i = c * 256 + t;
        int row = i >> 4, qp = i & 15;
        int sr = sidx[row];
        *(float4*)&qs[row * 68 + qp * 4] =
            *(const float4*)(q32 + (size_t)(b * S_ + sr) * E_ + h * 64 + qp * 4);
    }
    __syncthreads();

    int tok = t >> 2, eq = t & 3;          // token row, e-quarter (16 e each)
    int sr = sidx[tok];
    float th = (float)sr * THSTEP;
    float cw = __cosf(th), sw = __sinf(th);

    f32x2 acc2[8];
#pragma unroll
    for (int e = 0; e < 8; e++) acc2[e] = (f32x2){0.f, 0.f};

    const float4* kvcb = (const float4*)&kvc[eq * 16];
    const float4* kvsb = (const float4*)&kvs[eq * 16];
    for (int d = 0; d < 64; ++d) {
        float qd = fmaxf(qs[tok * 68 + d], 0.f);
        f32x2 a2 = { qd * cw, qd * cw };
        f32x2 b2 = { qd * sw, qd * sw };
#pragma unroll
        for (int c = 0; c < 4; ++c) {
            float4 c4 = kvcb[d * 16 + c];
            float4 s4 = kvsb[d * 16 + c];
            f32x2 c01 = { c4.x, c4.y }, c23 = { c4.z, c4.w };
            f32x2 s01 = { s4.x, s4.y }, s23 = { s4.z, s4.w };
            acc2[c * 2 + 0] += a2 * c01 + b2 * s01;
            acc2[c * 2 + 1] += a2 * c23 + b2 * s23;
        }
    }

    float* dst = out + (size_t)(b * S_ + sr) * E_ + h * 64 + eq * 16;
#pragma unroll
    for (int c = 0; c < 4; ++c) {
        float4 o = { acc2[c * 2 + 0][0], acc2[c * 2 + 0][1],
                     acc2[c * 2 + 1][0], acc2[c * 2 + 1][1] };
        *(float4*)(dst + c * 4) = o;
    }
}

extern "C" void kernel_launch(void* const* d_in, const int* in_sizes, int n_in,
                              void* d_out, int out_size, void* d_ws, size_t ws_size,
                              hipStream_t stream)
{
    const float* x  = (const float*)d_in[0];
    const float* Wq = (const float*)d_in[1];
    const float* bq = (const float*)d_in[2];
    const float* Wk = (const float*)d_in[3];
    const float* bk = (const float*)d_in[4];
    const float* Wv = (const float*)d_in[5];
    const float* bv = (const float*)d_in[6];

    char* ws = (char*)d_ws;
    ushort* xh     = (ushort*)(ws);                   // 33,554,432 B
    float*  kvp    = (float*)(ws);                    // aliases xh (dead after GEMM)
    float*  q32    = (float*)(ws + 33554432);         // 67,108,864 B
    float*  k32    = (float*)(ws + 100663296);        // 67,108,864 B
    ushort* v16    = (ushort*)(ws + 167772160);       // 33,554,432 B
    ushort* Wqh    = (ushort*)(ws + 201326592);       //  2,097,152 B
    ushort* Wql    = (ushort*)(ws + 203423744);
    ushort* Wkh    = (ushort*)(ws + 205520896);
    ushort* Wkl    = (ushort*)(ws + 207618048);
    ushort* Wvh    = (ushort*)(ws + 209715200);
    float*  scores = (float*)(ws + 211812352);        //  1,048,576 B
    int*    selidx = (int*)(ws + 212860928);          //    262,144 B
    int*    band   = (int*)(ws + 213123072);          //     24,576 B
    double* bscore = (double*)(ws + 213147648);       //     49,152 B
    int*    meta   = (int*)(ws + 213196800);          //        512 B
    float*  kv     = (float*)(ws + 213197312);        //  2,097,152 B (end ~205.3 MiB)
    float*  out    = (float*)d_out;

    hipLaunchKernelGGL(prep_kernel, dim3(4096), dim3(256), 0, stream,
                       x, Wq, Wk, Wv, xh, Wqh, Wql, Wkh, Wkl, Wvh, (uint4*)out);
    hipLaunchKernelGGL(qkv_gemm, dim3(128, 8, 3), dim3(256), 0, stream,
                       xh, Wqh, Wql, Wkh, Wkl, Wvh, bq, bk, bv, q32, k32, v16);
    hipLaunchKernelGGL(scores_kernel, dim3((B_ * H_ * S_) / 16), dim3(256), 0, stream,
                       q32, k32, scores);
    hipLaunchKernelGGL(band_select_kernel, dim3(B_ * H_), dim3(256), 0, stream,
                       scores, selidx, band, meta);
    hipLaunchKernelGGL(band_exact_kernel, dim3(BANDCAP, B_ * H_), dim3(512), 0, stream,
                       x, Wq, Wk, band, meta, bscore);
    hipLaunchKernelGGL(band_rank_kernel, dim3(B_ * H_), dim3(128), 0, stream,
                       bscore, band, meta, selidx);
    hipLaunchKernelGGL(kv_mfma_kernel, dim3(16, 64), dim3(256), 0, stream,
                       k32, v16, kvp);
    hipLaunchKernelGGL(kv_reduce_kernel, dim3(2048), dim3(256), 0, stream,
                       kvp, kv);
    hipLaunchKernelGGL(sampled_kernel, dim3(NS_ / 64, B_ * H_), dim3(256), 0, stream,
                       q32, selidx, kv, out);
}